// Round 1
// baseline (182.743 us; speedup 1.0000x reference)
//
#include <hip/hip_runtime.h>

// HitTheMiddleModel: per-row physics sim + 1e-10 * tiny linear.
// Memory-bound streaming: ~201 MB total traffic -> ~32 us floor at 6.3 TB/s.
// Each thread handles 4 rows (12 floats = 3 x float4) for 16B/lane vector
// memory ops.

__device__ __forceinline__ void sim_row(float x0, float x1, float x2,
                                        const float* Wv, const float* bv,
                                        float& o0, float& o1, float& o2) {
    float vel = x1 + x2;
    float pos = x0 + vel;
    bool hit = (pos > 10.0f) || (pos < -10.0f);
    vel = hit ? -vel : vel;
    pos = fminf(10.0f, fmaxf(-10.0f, pos));
    float reward = -pos * pos;
    // y = x @ W^T + b  (W row-major [3,3])
    float y0 = fmaf(x0, Wv[0], fmaf(x1, Wv[1], fmaf(x2, Wv[2], bv[0])));
    float y1 = fmaf(x0, Wv[3], fmaf(x1, Wv[4], fmaf(x2, Wv[5], bv[1])));
    float y2 = fmaf(x0, Wv[6], fmaf(x1, Wv[7], fmaf(x2, Wv[8], bv[2])));
    o0 = fmaf(1e-10f, y0, pos);
    o1 = fmaf(1e-10f, y1, vel);
    o2 = fmaf(1e-10f, y2, reward);
}

__global__ __launch_bounds__(256) void HitTheMiddleModel_kernel(
        const float4* __restrict__ X4,
        const float* __restrict__ W,
        const float* __restrict__ B,
        float4* __restrict__ O4,
        const float* __restrict__ X,
        float* __restrict__ O,
        int quads, int rem) {
    int t = blockIdx.x * blockDim.x + threadIdx.x;

    // W/b are wave-uniform -> scalar loads, cached.
    float Wv[9];
#pragma unroll
    for (int i = 0; i < 9; ++i) Wv[i] = W[i];
    float bv[3] = {B[0], B[1], B[2]};

    if (t < quads) {
        // 4 rows = 3 contiguous float4 per thread.
        const long long base = 3LL * t;
        float4 v0 = X4[base + 0];
        float4 v1 = X4[base + 1];
        float4 v2 = X4[base + 2];
        float4 r0, r1, r2;
        sim_row(v0.x, v0.y, v0.z, Wv, bv, r0.x, r0.y, r0.z);
        sim_row(v0.w, v1.x, v1.y, Wv, bv, r0.w, r1.x, r1.y);
        sim_row(v1.z, v1.w, v2.x, Wv, bv, r1.z, r1.w, r2.x);
        sim_row(v2.y, v2.z, v2.w, Wv, bv, r2.y, r2.z, r2.w);
        O4[base + 0] = r0;
        O4[base + 1] = r1;
        O4[base + 2] = r2;
    } else if (t < quads + rem) {
        // Tail rows (not hit for B = 8388608, kept for robustness).
        long long row = 4LL * quads + (t - quads);
        float x0 = X[3 * row + 0], x1 = X[3 * row + 1], x2 = X[3 * row + 2];
        float o0, o1, o2;
        sim_row(x0, x1, x2, Wv, bv, o0, o1, o2);
        O[3 * row + 0] = o0;
        O[3 * row + 1] = o1;
        O[3 * row + 2] = o2;
    }
}

extern "C" void kernel_launch(void* const* d_in, const int* in_sizes, int n_in,
                              void* d_out, int out_size, void* d_ws, size_t ws_size,
                              hipStream_t stream) {
    const float* x = (const float*)d_in[0];
    const float* W = (const float*)d_in[1];
    const float* b = (const float*)d_in[2];
    float* out = (float*)d_out;

    long long nfloats = (long long)in_sizes[0];
    long long rows = nfloats / 3;
    long long quads = rows / 4;
    int rem = (int)(rows - 4 * quads);

    long long nthreads = quads + rem;
    const int block = 256;
    long long grid = (nthreads + block - 1) / block;

    HitTheMiddleModel_kernel<<<(int)grid, block, 0, stream>>>(
        (const float4*)x, W, b, (float4*)out, x, out, (int)quads, rem);
}

// Round 2
// 177.429 us; speedup vs baseline: 1.0299x; 1.0299x over previous
//
#include <hip/hip_runtime.h>

// HitTheMiddleModel: per-row physics sim + 1e-10 * tiny linear.
// R2: fully lane-contiguous memory. Thread q owns output float4 O4[q] and
// loads the overlapping input window X4[q-1..q+1] (12 floats). That window
// always contains the 3-float rows feeding output floats 4q..4q+3, for any
// phase m = q%3. All global loads/stores are perfectly coalesced
// (16 B/lane, consecutive lanes -> consecutive addresses); the 3x L1 re-read
// from window overlap never reaches HBM. No LDS, no syncs.
//
// R1 post-mortem: the 4-rows-per-thread layout made every vector mem op a
// stride-48B lane pattern -> 48 cacheline transactions per instruction vs 16
// -> capped at 2.45 TB/s while fillBuffer hits 6.5 TB/s.

__device__ __forceinline__ void sim_row(float x0, float x1, float x2,
                                        const float* Wv, const float* bv,
                                        float& pos_o, float& vel_o, float& rew_o) {
    float vel = x1 + x2;
    float pos = x0 + vel;
    bool hit = (pos > 10.0f) || (pos < -10.0f);
    vel = hit ? -vel : vel;
    pos = fminf(10.0f, fmaxf(-10.0f, pos));
    float reward = -pos * pos;
    // y = x @ W^T + b  (W row-major [3,3]); weighted 1e-10 in the output.
    float y0 = fmaf(x0, Wv[0], fmaf(x1, Wv[1], fmaf(x2, Wv[2], bv[0])));
    float y1 = fmaf(x0, Wv[3], fmaf(x1, Wv[4], fmaf(x2, Wv[5], bv[1])));
    float y2 = fmaf(x0, Wv[6], fmaf(x1, Wv[7], fmaf(x2, Wv[8], bv[2])));
    pos_o = fmaf(1e-10f, y0, pos);
    vel_o = fmaf(1e-10f, y1, vel);
    rew_o = fmaf(1e-10f, y2, reward);
}

__global__ __launch_bounds__(256) void HitTheMiddleModel_kernel(
        const float4* __restrict__ X4,
        const float* __restrict__ W,
        const float* __restrict__ B,
        float4* __restrict__ O4,
        const float* __restrict__ X,
        float* __restrict__ O,
        int n4, int rem) {
    int q = blockIdx.x * blockDim.x + threadIdx.x;

    // W/b are wave-uniform -> scalar loads, cached.
    float Wv[9];
#pragma unroll
    for (int i = 0; i < 9; ++i) Wv[i] = W[i];
    float bv[3] = {B[0], B[1], B[2]};

    if (q < n4) {
        int iL = (q > 0) ? q - 1 : 0;            // clamped; junk never consumed
        int iR = (q < n4 - 1) ? q + 1 : q;
        float4 Lv = X4[iL];
        float4 Cv = X4[q];
        float4 Rv = X4[iR];
        // w[idx] <-> global float index (4q - 4 + idx)
        float w0 = Lv.x, w1 = Lv.y, w2 = Lv.z, w3 = Lv.w;
        float w4 = Cv.x, w5 = Cv.y, w6 = Cv.z, w7 = Cv.w;
        float w8 = Rv.x, w9 = Rv.y; // w10, w11 never needed

        int m = q % 3;  // phase: alignment of float 4q within its row
        float4 r;
        float pA, vA, rA, pB, vB, rB;
        if (m == 0) {
            // floats 4q..4q+2 = full row A (w4..w6); 4q+3 = pos of row B (w7..w9)
            sim_row(w4, w5, w6, Wv, bv, pA, vA, rA);
            sim_row(w7, w8, w9, Wv, bv, pB, vB, rB);
            r = make_float4(pA, vA, rA, pB);
        } else if (m == 1) {
            // 4q = vel of row A (w3..w5); 4q+2,4q+3 = pos,vel of row B (w6..w8)
            sim_row(w3, w4, w5, Wv, bv, pA, vA, rA);
            sim_row(w6, w7, w8, Wv, bv, pB, vB, rB);
            r = make_float4(vA, rA, pB, vB);
        } else {
            // 4q = reward of row A (w2..w4); 4q+1..4q+3 = row B (w5..w7)
            sim_row(w2, w3, w4, Wv, bv, pA, vA, rA);
            sim_row(w5, w6, w7, Wv, bv, pB, vB, rB);
            r = make_float4(rA, pB, vB, rB);
        }
        O4[q] = r;
    } else if (q < n4 + rem) {
        // Scalar tail for total floats not divisible by 4 (not hit for B=2^23).
        long long g = 4LL * n4 + (q - n4);
        long long row = g / 3;
        int c = (int)(g % 3);
        float x0 = X[3 * row], x1 = X[3 * row + 1], x2 = X[3 * row + 2];
        float p, v, rw;
        sim_row(x0, x1, x2, Wv, bv, p, v, rw);
        O[g] = (c == 0) ? p : (c == 1) ? v : rw;
    }
}

extern "C" void kernel_launch(void* const* d_in, const int* in_sizes, int n_in,
                              void* d_out, int out_size, void* d_ws, size_t ws_size,
                              hipStream_t stream) {
    const float* x = (const float*)d_in[0];
    const float* W = (const float*)d_in[1];
    const float* b = (const float*)d_in[2];
    float* out = (float*)d_out;

    long long nfloats = (long long)in_sizes[0];   // = 3 * rows
    long long n4 = nfloats / 4;                   // full float4s
    int rem = (int)(nfloats - 4 * n4);            // leftover floats (0 here)

    long long nthreads = n4 + rem;
    const int block = 256;
    long long grid = (nthreads + block - 1) / block;

    HitTheMiddleModel_kernel<<<(int)grid, block, 0, stream>>>(
        (const float4*)x, W, b, (float4*)out, x, out, (int)n4, rem);
}